// Round 5
// baseline (871.989 us; speedup 1.0000x reference)
//
#include <hip/hip_runtime.h>
#include <hip/hip_bf16.h>

// Attention_919123001813 — B=4, N=2048, DIM=1024, H=16, HD=64, SCALE=1/8
// Round 5: fp32 I/O, bf16 internal pipeline. Fix R3/R4 bug: attn grid was
// 16x too small (128 blocks = 512 waves for 8192 wave-tasks) — only b=0,
// h<4 computed; rest of ctx stayed ws-poison (~3e-13) -> out ~ 0.

typedef short bf16x8 __attribute__((ext_vector_type(8)));
typedef float f32x4  __attribute__((ext_vector_type(4)));

#define BN   4
#define SEQ  2048
#define CDIM 1024
#define NH   16
#define HD   64
#define QKVN 3072
#define MTOT 8192   // BN*SEQ
#define SCALE 0.125f

static __device__ __forceinline__ unsigned short f2bf(float f){
    union { float f; unsigned int i; } v; v.f = f;
    unsigned int r = v.i + 0x7FFFu + ((v.i >> 16) & 1u);   // RNE
    return (unsigned short)(r >> 16);
}

// ---------------- 32x32 tiled transpose: fp32 in -> bf16 out ---------------
// block (32,8): thread handles rows ty+8j of the tile, j=0..3.
__global__ __launch_bounds__(256) void transpose_f32_to_bf16(
    const float* __restrict__ in, unsigned short* __restrict__ out,
    int in_rs, int out_rs)
{
    __shared__ unsigned short tile[32][33];
    int c0 = blockIdx.x * 32, r0 = blockIdx.y * 32;
    int tx = threadIdx.x, ty = threadIdx.y;
    #pragma unroll
    for (int j = 0; j < 4; j++)
        tile[ty + 8*j][tx] = f2bf(in[(long long)(r0 + ty + 8*j) * in_rs + c0 + tx]);
    __syncthreads();
    #pragma unroll
    for (int j = 0; j < 4; j++)
        out[(long long)(c0 + ty + 8*j) * out_rs + r0 + tx] = tile[tx][ty + 8*j];
}

// ---------------- 32x32 tiled transpose: bf16 -> bf16 (z-batched) ----------
__global__ __launch_bounds__(256) void transpose_b16(
    const unsigned short* __restrict__ in, unsigned short* __restrict__ out,
    int in_rs, int out_rs, long long in_zs, long long out_zs)
{
    __shared__ unsigned short tile[32][33];
    int z = blockIdx.z;
    in  += (long long)z * in_zs;
    out += (long long)z * out_zs;
    int c0 = blockIdx.x * 32, r0 = blockIdx.y * 32;
    int tx = threadIdx.x, ty = threadIdx.y;
    #pragma unroll
    for (int j = 0; j < 4; j++)
        tile[ty + 8*j][tx] = in[(long long)(r0 + ty + 8*j) * in_rs + c0 + tx];
    __syncthreads();
    #pragma unroll
    for (int j = 0; j < 4; j++)
        out[(long long)(c0 + ty + 8*j) * out_rs + r0 + tx] = tile[tx][ty + 8*j];
}

// ---------------- GEMM: C[m][n] = sum_k A[m][k] * BT[n][k] (+bias[n]) ------
// block = 256 thr = 4 waves; block tile 128x128; wave tile 64x64 (4x4 mfma).
// AF32: A is fp32, converted to bf16 in-register. OUTF32: C is fp32.
template<bool AF32, bool OUTF32>
__global__ __launch_bounds__(256) void gemm_bt(
    const void* __restrict__ Av,             // [M,K] row-major (fp32 or bf16)
    const unsigned short* __restrict__ BT,   // [N,K] row-major bf16
    void* __restrict__ Cv,                   // [M,Cstride] (bf16 or fp32)
    const float* __restrict__ bias,          // [N] fp32 or nullptr
    int K, int Cstride)
{
    int tid  = threadIdx.x;
    int wave = tid >> 6, lane = tid & 63, quad = lane >> 4, l15 = lane & 15;
    int m0 = blockIdx.y * 128 + (wave & 1) * 64;
    int n0 = blockIdx.x * 128 + (wave >> 1) * 64;

    const float*          Af = (const float*)Av;
    const unsigned short* Ab = (const unsigned short*)Av;

    size_t a_off[4];
    const unsigned short* b_ptr[4];
    #pragma unroll
    for (int i = 0; i < 4; i++) {
        a_off[i] = (size_t)(m0 + 16*i + l15) * K + quad * 8;
        b_ptr[i] = BT + (size_t)(n0 + 16*i + l15) * K + quad * 8;
    }

    f32x4 acc[4][4];
    #pragma unroll
    for (int i = 0; i < 4; i++)
        #pragma unroll
        for (int j = 0; j < 4; j++)
            acc[i][j] = f32x4{0.f, 0.f, 0.f, 0.f};

    for (int k0 = 0; k0 < K; k0 += 32) {
        bf16x8 af[4], bf[4];
        #pragma unroll
        for (int i = 0; i < 4; i++) {
            if (AF32) {
                f32x4 f0 = *(const f32x4*)(Af + a_off[i]);
                f32x4 f1 = *(const f32x4*)(Af + a_off[i] + 4);
                #pragma unroll
                for (int j = 0; j < 4; j++) {
                    af[i][j]   = (short)f2bf(f0[j]);
                    af[i][4+j] = (short)f2bf(f1[j]);
                }
            } else {
                af[i] = *(const bf16x8*)(Ab + a_off[i]);
            }
        }
        #pragma unroll
        for (int i = 0; i < 4; i++) bf[i] = *(const bf16x8*)(b_ptr[i]);
        #pragma unroll
        for (int i = 0; i < 4; i++) { a_off[i] += 32; b_ptr[i] += 32; }
        #pragma unroll
        for (int mi = 0; mi < 4; mi++)
            #pragma unroll
            for (int ni = 0; ni < 4; ni++)
                acc[mi][ni] = __builtin_amdgcn_mfma_f32_16x16x32_bf16(
                                  af[mi], bf[ni], acc[mi][ni], 0, 0, 0);
    }

    // C/D layout: col = lane&15, row = quad*4 + reg  [verified m89/m91]
    #pragma unroll
    for (int ni = 0; ni < 4; ni++) {
        int col = n0 + 16*ni + l15;
        float bv = bias ? bias[col] : 0.f;
        #pragma unroll
        for (int mi = 0; mi < 4; mi++)
            #pragma unroll
            for (int r = 0; r < 4; r++) {
                int row = m0 + 16*mi + quad*4 + r;
                float v = acc[mi][ni][r] + bv;
                if (OUTF32) ((float*)Cv)[(size_t)row * Cstride + col] = v;
                else ((unsigned short*)Cv)[(size_t)row * Cstride + col] = f2bf(v);
            }
    }
}

// ---------------- Flash attention, one wave per 16-row Q strip -------------
// 32 keys/iter. S^T = K·Q^T as two 16x16 C-tiles with permuted key rows:
// A-row m of tile t holds K row j0 + (m>>2)*8 + t*4 + (m&3), so C reg r of
// tile t holds key quad*8 + t*4 + r -> lane ends with keys quad*8+{0..7},
// exactly the K=32 A-operand layout A[m=l15][k=quad*8+j] needed for P·V.
__global__ __launch_bounds__(256) void attn_kernel(
    const unsigned short* __restrict__ qkv,  // [MTOT, 3072]  (Q | K | V cols)
    const unsigned short* __restrict__ vT,   // [BN][CDIM][SEQ]
    unsigned short* __restrict__ ctx)        // [MTOT, 1024]
{
    int tid  = threadIdx.x;
    int wave = tid >> 6, lane = tid & 63, quad = lane >> 4, l15 = lane & 15;
    int gw    = blockIdx.x * 4 + wave;     // 0..8191 (BN*NH*128 wave-tasks)
    int bh    = gw >> 7;                   // 0..63  (SEQ/16 = 128 strips/bh)
    int strip = gw & 127;
    int b = bh >> 4, h = bh & 15;
    int i0 = strip * 16;

    // Q fragments (loop-invariant): B-operand, n = lane&15 = query row i
    const unsigned short* qbase =
        qkv + (size_t)(b*SEQ + i0 + l15) * QKVN + h*HD + quad*8;
    bf16x8 qf0 = *(const bf16x8*)(qbase);
    bf16x8 qf1 = *(const bf16x8*)(qbase + 32);

    // K row permutation for the two S^T tiles
    int krow0 = (l15 >> 2)*8 + (l15 & 3);        // tile 0
    const unsigned short* kp0 =
        qkv + (size_t)(b*SEQ + krow0) * QKVN + CDIM + h*HD + quad*8;
    const unsigned short* kp1 = kp0 + (size_t)4 * QKVN;   // tile 1: +4 keys

    // V pointers: B[k=j][n=d], d = db*16 + l15, j = j0 + quad*8 + 0..7
    const unsigned short* vp[4];
    #pragma unroll
    for (int db = 0; db < 4; db++)
        vp[db] = vT + (size_t)(b*CDIM + h*HD + db*16 + l15) * SEQ + quad*8;

    f32x4 o[4];
    #pragma unroll
    for (int i = 0; i < 4; i++) o[i] = f32x4{0.f, 0.f, 0.f, 0.f};
    float m = -INFINITY, l = 0.f;

    for (int t = 0; t < SEQ/32; t++) {
        bf16x8 k0a = *(const bf16x8*)(kp0);
        bf16x8 k0b = *(const bf16x8*)(kp0 + 32);
        bf16x8 k1a = *(const bf16x8*)(kp1);
        bf16x8 k1b = *(const bf16x8*)(kp1 + 32);
        kp0 += (size_t)32 * QKVN;
        kp1 += (size_t)32 * QKVN;

        f32x4 s0 = f32x4{0.f, 0.f, 0.f, 0.f};
        f32x4 s1 = f32x4{0.f, 0.f, 0.f, 0.f};
        s0 = __builtin_amdgcn_mfma_f32_16x16x32_bf16(k0a, qf0, s0, 0, 0, 0);
        s0 = __builtin_amdgcn_mfma_f32_16x16x32_bf16(k0b, qf1, s0, 0, 0, 0);
        s1 = __builtin_amdgcn_mfma_f32_16x16x32_bf16(k1a, qf0, s1, 0, 0, 0);
        s1 = __builtin_amdgcn_mfma_f32_16x16x32_bf16(k1b, qf1, s1, 0, 0, 0);
        // lane holds S[i=l15][key quad*8+r] (s0) and [key quad*8+4+r] (s1)

        float sv[8];
        #pragma unroll
        for (int r = 0; r < 4; r++) { sv[r] = s0[r]*SCALE; sv[4+r] = s1[r]*SCALE; }
        float tm = sv[0];
        #pragma unroll
        for (int j = 1; j < 8; j++) tm = fmaxf(tm, sv[j]);
        tm = fmaxf(tm, __shfl_xor(tm, 16));
        tm = fmaxf(tm, __shfl_xor(tm, 32));
        float mn = fmaxf(m, tm);
        float alpha = __expf(m - mn);            // first iter: exp(-inf)=0
        float p[8], rs = 0.f;
        #pragma unroll
        for (int j = 0; j < 8; j++) { p[j] = __expf(sv[j] - mn); rs += p[j]; }
        rs += __shfl_xor(rs, 16);
        rs += __shfl_xor(rs, 32);
        l = l * alpha + rs;
        m = mn;

        // rescale O: acc reg r is output row quad*4+r; lane quad*4+r (l15 ==
        // that row) holds its alpha
        #pragma unroll
        for (int r = 0; r < 4; r++) {
            float ar = __shfl(alpha, quad*4 + r);
            o[0][r] *= ar; o[1][r] *= ar; o[2][r] *= ar; o[3][r] *= ar;
        }

        // P fragment: A[m=l15][k=quad*8+j] = p[j]
        bf16x8 pa;
        #pragma unroll
        for (int j = 0; j < 8; j++) pa[j] = (short)f2bf(p[j]);

        #pragma unroll
        for (int db = 0; db < 4; db++) {
            bf16x8 vb = *(const bf16x8*)(vp[db]);
            vp[db] += 32;
            o[db] = __builtin_amdgcn_mfma_f32_16x16x32_bf16(pa, vb, o[db], 0, 0, 0);
        }
    }

    // epilogue: normalize rows and store ctx[b, i, h*64 + d]
    #pragma unroll
    for (int r = 0; r < 4; r++) {
        float lr  = __shfl(l, quad*4 + r);
        float inv = 1.f / lr;
        int row = b*SEQ + i0 + quad*4 + r;
        #pragma unroll
        for (int db = 0; db < 4; db++)
            ctx[(size_t)row * CDIM + h*HD + db*16 + l15] = f2bf(o[db][r] * inv);
    }
}

// ---------------------------------------------------------------------------
extern "C" void kernel_launch(void* const* d_in, const int* in_sizes, int n_in,
                              void* d_out, int out_size, void* d_ws, size_t ws_size,
                              hipStream_t stream)
{
    const float* x      = (const float*)d_in[0]; // [8192,1024] fp32
    const float* w_qkv  = (const float*)d_in[1]; // [1024,3072] fp32
    const float* w_proj = (const float*)d_in[2]; // [1024,1024] fp32
    const float* b_proj = (const float*)d_in[3]; // [1024]      fp32
    float* out = (float*)d_out;                  // [8192,1024] fp32

    char* ws = (char*)d_ws;                                      // 88 MiB used
    unsigned short* qkv    = (unsigned short*)(ws);              // 50,331,648 B
    unsigned short* vT     = (unsigned short*)(ws + 50331648);   // 16,777,216 B
    unsigned short* ctx    = (unsigned short*)(ws + 67108864);   // 16,777,216 B
    unsigned short* wqkvT  = (unsigned short*)(ws + 83886080);   //  6,291,456 B
    unsigned short* wprojT = (unsigned short*)(ws + 90177536);   //  2,097,152 B

    dim3 tb(32, 8);
    // weight transposes (fp32 -> bf16, [K,N] -> [N,K])
    transpose_f32_to_bf16<<<dim3(QKVN/32, CDIM/32), tb, 0, stream>>>(
        w_qkv, wqkvT, QKVN, CDIM);
    transpose_f32_to_bf16<<<dim3(CDIM/32, CDIM/32), tb, 0, stream>>>(
        w_proj, wprojT, CDIM, CDIM);

    // qkv = bf16(x) @ wqkvT   [8192, 3072] bf16
    gemm_bt<true, false><<<dim3(QKVN/128, MTOT/128), 256, 0, stream>>>(
        x, wqkvT, qkv, nullptr, CDIM, QKVN);

    // vT[b][d][n] = V[b][n][d]  (V = qkv cols 2048..3071)
    transpose_b16<<<dim3(CDIM/32, SEQ/32, BN), tb, 0, stream>>>(
        qkv + 2*CDIM, vT, QKVN, SEQ,
        (long long)SEQ * QKVN, (long long)CDIM * SEQ);

    // flash attention -> ctx [8192, 1024] bf16
    // wave-tasks = BN*NH*(SEQ/16) = 8192 -> 2048 blocks of 4 waves
    attn_kernel<<<dim3(BN * NH * (SEQ/16) / 4), 256, 0, stream>>>(qkv, vT, ctx);

    // out = ctx @ wprojT + b_proj   (fp32 out)
    gemm_bt<false, true><<<dim3(CDIM/128, MTOT/128), 256, 0, stream>>>(
        ctx, wprojT, out, b_proj, CDIM, CDIM);
}